// Round 7
// baseline (612.149 us; speedup 1.0000x reference)
//
#include <hip/hip_runtime.h>

typedef short s16x8 __attribute__((ext_vector_type(8)));
typedef float f32x4 __attribute__((ext_vector_type(4)));
typedef unsigned int u32x2 __attribute__((ext_vector_type(2)));
typedef unsigned short u16;
typedef unsigned int u32;

#define D_MODEL 1024
#define NHEAD   16
#define HD      64
#define TSEQ    2048
#define NB      2
#define MROWS   4096   // B*T
#define NSPLIT  2
#define NTILES  (TSEQ / 64 / NSPLIT)   // 16 kv tiles per split

#define LOG2E 1.4426950408889634f
#define QSCALE (0.125f * LOG2E)   // folded into Q projection epilogue

__device__ __forceinline__ u16 f2bf(float f) {
  unsigned u = __builtin_bit_cast(unsigned, f);
  u += 0x7fffu + ((u >> 16) & 1u);
  return (u16)(u >> 16);
}

__device__ __forceinline__ float bf2f(u16 x) {
  return __builtin_bit_cast(float, (u32)x << 16);
}

__device__ __forceinline__ u32 cvtpk(float lo, float hi) {
  u32 r;
  asm("v_cvt_pk_bf16_f32 %0, %1, %2" : "=v"(r) : "v"(lo), "v"(hi));
  return r;
}

__device__ __forceinline__ float exp2fast(float x) {
#if __has_builtin(__builtin_amdgcn_exp2f)
  return __builtin_amdgcn_exp2f(x);
#else
  return exp2f(x);
#endif
}

__device__ __forceinline__ float rcpfast(float x) {
#if __has_builtin(__builtin_amdgcn_rcpf)
  return __builtin_amdgcn_rcpf(x);
#else
  return 1.f / x;
#endif
}

__device__ __forceinline__ void gload16(const void* g, void* l) {
  __builtin_amdgcn_global_load_lds((const __attribute__((address_space(1))) void*)g,
                                   (__attribute__((address_space(3))) void*)l,
                                   16, 0, 0);
}

// ---------------- fused fp32->bf16 converts + bias_sum (one dispatch) ----------------
__global__ void cvt_all(const float* __restrict__ q, const float* __restrict__ k,
                        const float* __restrict__ v, const float* __restrict__ wq,
                        const float* __restrict__ wk, const float* __restrict__ wv,
                        const float* __restrict__ wo, const float* __restrict__ ab,
                        u16* qb, u16* kb, u16* vb, u16* wqb, u16* wkb, u16* wvb, u16* wob,
                        float* bsum) {
  if (blockIdx.x == 16384) {
    if (threadIdx.x < 64) {
      float s = ab[threadIdx.x];
#pragma unroll
      for (int m = 32; m >= 1; m >>= 1) s += __shfl_xor(s, m);
      if (threadIdx.x == 0) bsum[0] = s * 0.125f * LOG2E;  // pre-fold scale*log2e
    }
    return;
  }
  int i = blockIdx.x * 256 + threadIdx.x;   // float4 index
  const float* src; u16* dst; int off;
  if (i < 3 * 1048576) {
    int t = i >> 20; off = i & 1048575;
    src = (t == 0) ? q : (t == 1) ? k : v;
    dst = (t == 0) ? qb : (t == 1) ? kb : vb;
  } else {
    int j = i - 3 * 1048576;
    int t = j >> 18; off = j & 262143;
    src = (t == 0) ? wq : (t == 1) ? wk : (t == 2) ? wv : wo;
    dst = (t == 0) ? wqb : (t == 1) ? wkb : (t == 2) ? wvb : wob;
  }
  float4 x = ((const float4*)src)[off];
  ushort4 o;
  o.x = f2bf(x.x); o.y = f2bf(x.y); o.z = f2bf(x.z); o.w = f2bf(x.w);
  ((ushort4*)dst)[off] = o;
}

// ---------------- double-buffered GEMM core: C = (A*Bt^T + bias)*oscale ----------------
// MODE 0: out bf16 (B,H,T,Dh);  MODE 1: out bf16 (B,H,Dh,T) via swapped-operand MFMA
// (acc holds C^T so the t-major stores coalesce);  MODE 2: out fp32 row-major.
template <int BM, int BN, int WN, int MODE>
__device__ __forceinline__ void gemm_core(const u16* __restrict__ A, const u16* __restrict__ Bt,
                                          const float* __restrict__ bias, void* __restrict__ out,
                                          float oscale, u16* lds) {
  constexpr int K = 1024, N = 1024;
  constexpr int WM = 4 / WN;
  constexpr int WTM = BM / WM, WTN = BN / WN;
  constexpr int MR = WTM / 16, NR = WTN / 16;
  constexpr int ASZ = BM * 32, BSZ = BN * 32;
  constexpr int AISS = ASZ / 2048, BISS = BSZ / 2048;
  u16* lA = lds;
  u16* lB = lds + 2 * ASZ;

  const int tid = threadIdx.x;
  const int wid = tid >> 6, lane = tid & 63;
  const int l15 = lane & 15, lgp = lane >> 4;
  const int wr = wid / WN, wc = wid % WN;
  const int m0 = blockIdx.y * BM, n0 = blockIdx.x * BN;

  const u16* gA[AISS];
  const u16* gB[BISS];
#pragma unroll
  for (int i = 0; i < AISS; ++i) {
    int tp = i * 256 + tid, row = tp % BM, kc = tp / BM;
    gA[i] = A + (size_t)(m0 + row) * K + kc * 8;
  }
#pragma unroll
  for (int i = 0; i < BISS; ++i) {
    int tp = i * 256 + tid, row = tp % BN, kc = tp / BN;
    gB[i] = Bt + (size_t)(n0 + row) * K + kc * 8;
  }

  f32x4 acc[MR][NR];
#pragma unroll
  for (int m = 0; m < MR; ++m)
#pragma unroll
    for (int n = 0; n < NR; ++n) acc[m][n] = (f32x4){0.f, 0.f, 0.f, 0.f};

  auto stage = [&](int buf, int k0) {
#pragma unroll
    for (int i = 0; i < AISS; ++i)
      gload16(gA[i] + k0, lA + buf * ASZ + (i * 256 + tid) * 8);
#pragma unroll
    for (int i = 0; i < BISS; ++i)
      gload16(gB[i] + k0, lB + buf * BSZ + (i * 256 + tid) * 8);
  };

  int cur = 0;
  stage(0, 0);
  __syncthreads();
  for (int k0 = 0; k0 < K; k0 += 32) {
    if (k0 + 32 < K) stage(cur ^ 1, k0 + 32);
    const u16* a = lA + cur * ASZ;
    const u16* b = lB + cur * BSZ;
    s16x8 af[MR], bf[NR];
#pragma unroll
    for (int m = 0; m < MR; ++m)
      af[m] = *(const s16x8*)(a + lgp * BM * 8 + (wr * WTM + m * 16 + l15) * 8);
#pragma unroll
    for (int n = 0; n < NR; ++n)
      bf[n] = *(const s16x8*)(b + lgp * BN * 8 + (wc * WTN + n * 16 + l15) * 8);
    __builtin_amdgcn_s_setprio(1);
#pragma unroll
    for (int m = 0; m < MR; ++m)
#pragma unroll
      for (int n = 0; n < NR; ++n) {
        if (MODE == 1)
          acc[m][n] = __builtin_amdgcn_mfma_f32_16x16x32_bf16(bf[n], af[m], acc[m][n], 0, 0, 0);
        else
          acc[m][n] = __builtin_amdgcn_mfma_f32_16x16x32_bf16(af[m], bf[n], acc[m][n], 0, 0, 0);
      }
    __builtin_amdgcn_s_setprio(0);
    __syncthreads();
    cur ^= 1;
  }

  if (MODE == 1) {
    // acc[m][n] = C^T tile: row (lgp*4+r) = n-dir (dmodel-out), col (l15) = m-dir (token)
    float4 bvv4[NR];
#pragma unroll
    for (int n = 0; n < NR; ++n)
      bvv4[n] = *(const float4*)(bias + n0 + wc * WTN + n * 16 + lgp * 4);
#pragma unroll
    for (int m = 0; m < MR; ++m) {
      int m_abs = m0 + wr * WTM + m * 16 + l15;
      int bb = m_abs >> 11, t = m_abs & 2047;
#pragma unroll
      for (int n = 0; n < NR; ++n) {
#pragma unroll
        for (int r = 0; r < 4; ++r) {
          int n_abs = n0 + wc * WTN + n * 16 + lgp * 4 + r;
          int h = n_abs >> 6, d = n_abs & 63;
          float vv = (acc[m][n][r] + ((const float*)&bvv4[n])[r]) * oscale;
          ((u16*)out)[(((size_t)((bb * NHEAD + h) * HD + d)) << 11) + t] = f2bf(vv);
        }
      }
    }
  } else {
    float bvv[NR];
#pragma unroll
    for (int n = 0; n < NR; ++n) bvv[n] = bias[n0 + wc * WTN + n * 16 + l15];
#pragma unroll
    for (int m = 0; m < MR; ++m) {
      int rowb = m0 + wr * WTM + m * 16 + lgp * 4;
#pragma unroll
      for (int n = 0; n < NR; ++n) {
        int col = n0 + wc * WTN + n * 16 + l15;
#pragma unroll
        for (int r = 0; r < 4; ++r) {
          int row = rowb + r;
          float vv = (acc[m][n][r] + bvv[n]) * oscale;
          if (MODE == 2) {
            ((float*)out)[(size_t)row * N + col] = vv;
          } else {
            int b = row >> 11, t = row & 2047;
            int h = col >> 6, d = col & 63;
            ((u16*)out)[(((size_t)(b * NHEAD + h) * TSEQ + t) << 6) + d] = f2bf(vv);
          }
        }
      }
    }
  }
}

__global__ __launch_bounds__(256) void gemm_qkv(const u16* __restrict__ qb, const u16* __restrict__ kb,
                                                const u16* __restrict__ vb,
                                                const u16* __restrict__ Wqb, const u16* __restrict__ Wkb,
                                                const u16* __restrict__ Wvb,
                                                const float* __restrict__ bq, const float* __restrict__ bk,
                                                const float* __restrict__ bv,
                                                u16* Qp, u16* Kp, u16* Vtp) {
  __shared__ __align__(16) u16 lds[2 * 128 * 32 * 2];   // 32 KB
  int z = blockIdx.z;
  if (z == 0)
    gemm_core<128, 128, 2, 0>(qb, Wqb, bq, Qp, QSCALE, lds);
  else if (z == 1)
    gemm_core<128, 128, 2, 0>(kb, Wkb, bk, Kp, 1.0f, lds);
  else
    gemm_core<128, 128, 2, 1>(vb, Wvb, bv, Vtp, 1.0f, lds);
}

__global__ __launch_bounds__(256) void gemm_out(const u16* __restrict__ A, const u16* __restrict__ Bt,
                                                const float* __restrict__ bias, float* __restrict__ out) {
  __shared__ __align__(16) u16 lds[2 * 64 * 32 + 2 * 128 * 32];   // 24 KB
  gemm_core<64, 128, 4, 2>(A, Bt, bias, out, 1.0f, lds);
}

// ---------------- flash attention, kv-split x2, 8 waves/block, 40KB LDS ----------------
// grid: (T/128, B*H, NSPLIT), block 512 = 8 waves. Wave w owns 16 q rows [bx*128+w*16, +16).
// K single-buffered (8KB), V double (16KB), per-wave plds (16KB) -> 4 blocks/CU = 32 waves/CU.
//   read K-frags -> sync1 -> stage K(t+1),V(t+1) -> QK -> softmax -> PV(vbuf[cur]) -> sync2
// Outputs UNNORMALIZED partial O (bf16) + per-row (m2, lsum) for the combine pass.
__global__ __launch_bounds__(512, 8) void attn_kernel(const u16* __restrict__ Qp,
                                                      const u16* __restrict__ Kp,
                                                      const u16* __restrict__ Vt,
                                                      const float* __restrict__ frac,
                                                      const float* __restrict__ bsum,
                                                      u16* __restrict__ o0,
                                                      u16* __restrict__ o1,
                                                      float2* __restrict__ ml) {
  __shared__ __align__(16) u16 kbuf[64 * 64];       // 8 KB (single-buffered)
  __shared__ __align__(16) u16 vbuf[2][64 * 64];    // 16 KB
  __shared__ __align__(16) u16 plds[8][16 * 64];    // 16 KB
  const int tid = threadIdx.x, wid = tid >> 6, lane = tid & 63;
  const int l15 = lane & 15, lgp = lane >> 4;
  const int bh = blockIdx.y, b = bh >> 4, h = bh & 15;
  const int z = blockIdx.z;
  const int kvbase = z * (TSEQ / NSPLIT);
  u16* opart = z ? o1 : o0;
  float2* mlz = ml + z * (NB * NHEAD * TSEQ);
  const u16* Qh = Qp + (size_t)bh * TSEQ * HD;
  const u16* Kh = Kp + (size_t)bh * TSEQ * HD;
  const u16* Vh = Vt + (size_t)bh * HD * TSEQ;
  const float* fb = frac + b * TSEQ;
  const float bs = bsum[0];                    // bias_sum * scale * log2e (pre-folded)
  const float THR2 = 24.0f;
  const int q0 = blockIdx.x * 128 + wid * 16;

  // staging lane constants (pre-swizzled global source, rule #21)
  const int srow = lane >> 3;                  // wave covers rows wid*8 .. wid*8+7
  const int sg8 = ((lane & 7) ^ srow) * 8;     // swizzled col8 * 8 (u16 units)
  const int rbase = wid * 8 + srow;

  // frag-read offsets (u16 units)
  const int ofs0 = l15 * 64 + ((lgp ^ (l15 & 7)) * 8);
  const int ofs1 = l15 * 64 + (((4 + lgp) ^ (l15 & 7)) * 8);

  // Q fragments (B-operand: lane l15 = q col, lgp*8 = dh slice)
  s16x8 qf[2];
#pragma unroll
  for (int ks = 0; ks < 2; ++ks)
    qf[ks] = *(const s16x8*)(Qh + (size_t)(q0 + l15) * HD + ks * 32 + lgp * 8);

  const float fi = fb[q0 + l15];
  const float nbfi = -bs * fi;
  float m2run = -1e30f;
  float lsum = 0.f;
  f32x4 o[4];
#pragma unroll
  for (int nd = 0; nd < 4; ++nd) o[nd] = (f32x4){0.f, 0.f, 0.f, 0.f};

  auto stageK = [&](int t) {
    int kv0s = kvbase + t * 64;
    gload16(Kh + (size_t)(kv0s + rbase) * HD + sg8, &kbuf[wid * 512]);
  };
  auto stageV = [&](int buf, int t) {
    int kv0s = kvbase + t * 64;
    gload16(Vh + (size_t)rbase * TSEQ + kv0s + sg8, &vbuf[buf][wid * 512]);
  };

  int cur = 0;
  stageK(0);
  stageV(0, 0);
  __syncthreads();

  for (int t = 0; t < NTILES; ++t) {
    // ---- grab K fragments from kbuf into registers
    s16x8 kf[4][2];
#pragma unroll
    for (int n = 0; n < 4; ++n) {
      kf[n][0] = *(const s16x8*)(&kbuf[0] + n * 1024 + ofs0);
      kf[n][1] = *(const s16x8*)(&kbuf[0] + n * 1024 + ofs1);
    }
    float4 fj4[4];
#pragma unroll
    for (int n = 0; n < 4; ++n)
      fj4[n] = *(const float4*)(fb + kvbase + t * 64 + n * 16 + lgp * 4);

    __syncthreads();   // sync1: all waves done reading kbuf
    if (t + 1 < NTILES) { stageK(t + 1); stageV(cur ^ 1, t + 1); }

    // ---- QK^T (swapped): s[n][r] = S_log2[kv][q0+l15]
    f32x4 s[4];
    __builtin_amdgcn_s_setprio(1);
#pragma unroll
    for (int n = 0; n < 4; ++n) {
      f32x4 a = (f32x4){0.f, 0.f, 0.f, 0.f};
      a = __builtin_amdgcn_mfma_f32_16x16x32_bf16(kf[n][0], qf[0], a, 0, 0, 0);
      a = __builtin_amdgcn_mfma_f32_16x16x32_bf16(kf[n][1], qf[1], a, 0, 0, 0);
      s[n] = a;
    }
    __builtin_amdgcn_s_setprio(0);

    // ---- logits (log2 domain): l2 = s + bs*(fj-fi)/(fi*fj+eps)
    float pmax = -1e30f;
#pragma unroll
    for (int n = 0; n < 4; ++n) {
#pragma unroll
      for (int r = 0; r < 4; ++r) {
        float fj = (r == 0) ? fj4[n].x : (r == 1) ? fj4[n].y : (r == 2) ? fj4[n].z : fj4[n].w;
        float num = __builtin_fmaf(bs, fj, nbfi);
        float den = __builtin_fmaf(fi, fj, 1e-8f);
        float l2 = __builtin_fmaf(num, rcpfast(den), s[n][r]);
        s[n][r] = l2;
        pmax = fmaxf(pmax, l2);
      }
    }

    // ---- rare rescale (speculative defer-max)
    if (__any((pmax - m2run) > THR2)) {
      float tm = fmaxf(pmax, __shfl_xor(pmax, 16));
      tm = fmaxf(tm, __shfl_xor(tm, 32));
      float m2n = fmaxf(m2run, tm);
      float alpha = exp2fast(m2run - m2n);
      lsum *= alpha;
      m2run = m2n;
      float af[4];
#pragma unroll
      for (int r = 0; r < 4; ++r) af[r] = __shfl(alpha, lgp * 4 + r);
#pragma unroll
      for (int nd = 0; nd < 4; ++nd)
#pragma unroll
        for (int r = 0; r < 4; ++r) o[nd][r] *= af[r];
    }

    // ---- P = exp2(l2 - m2run), pack bf16, partial row-sum
    u32 w[4][2];
    {
      float ps = 0.f;
#pragma unroll
      for (int n = 0; n < 4; ++n) {
#pragma unroll
        for (int s2 = 0; s2 < 2; ++s2) {
          float p0 = exp2fast(s[n][2 * s2 + 0] - m2run);
          float p1 = exp2fast(s[n][2 * s2 + 1] - m2run);
          ps += p0 + p1;
          w[n][s2] = cvtpk(p0, p1);
        }
      }
      lsum += ps;
    }

    // ---- P -> per-wave LDS (swizzled) -> A-operand frags
    u16* pw = &plds[wid][0];
#pragma unroll
    for (int n = 0; n < 4; ++n) {
      int idx = l15 * 64 + ((n * 16 + lgp * 4) ^ ((l15 & 7) << 3));
      *(u32x2*)(pw + idx) = (u32x2){w[n][0], w[n][1]};
    }
    s16x8 pf[2];
#pragma unroll
    for (int ks = 0; ks < 2; ++ks) {
      int idx = l15 * 64 + ((ks * 32 + lgp * 8) ^ ((l15 & 7) << 3));
      pf[ks] = *(const s16x8*)(pw + idx);
    }

    // ---- PV: o[nd] += P * V
    const u16* vbp = &vbuf[cur][0];
    __builtin_amdgcn_s_setprio(1);
#pragma unroll
    for (int nd = 0; nd < 4; ++nd) {
      s16x8 vf0 = *(const s16x8*)(vbp + nd * 1024 + ofs0);
      s16x8 vf1 = *(const s16x8*)(vbp + nd * 1024 + ofs1);
      o[nd] = __builtin_amdgcn_mfma_f32_16x16x32_bf16(pf[0], vf0, o[nd], 0, 0, 0);
      o[nd] = __builtin_amdgcn_mfma_f32_16x16x32_bf16(pf[1], vf1, o[nd], 0, 0, 0);
    }
    __builtin_amdgcn_s_setprio(0);

    __syncthreads();   // sync2: drains staged gloads, protects vbuf/kbuf
    cur ^= 1;
  }

  // ---- epilogue: reduce lsum across lgp, store (m,l) + unnormalized partial O
  {
    float l = lsum;
    l += __shfl_xor(l, 16);
    l += __shfl_xor(l, 32);
    if (lgp == 0)
      mlz[(bh << 11) + q0 + l15] = make_float2(m2run, l);
#pragma unroll
    for (int nd = 0; nd < 4; ++nd)
#pragma unroll
      for (int r = 0; r < 4; ++r) {
        int q = q0 + lgp * 4 + r;
        opart[((size_t)(b * TSEQ + q)) * D_MODEL + h * HD + nd * 16 + l15] = f2bf(o[nd][r]);
      }
  }
}

// ---------------- combine the 2 kv-splits ----------------
__global__ __launch_bounds__(256) void attn_combine(const u16* __restrict__ o0,
                                                    const u16* __restrict__ o1,
                                                    const float2* __restrict__ ml,
                                                    u16* __restrict__ aout) {
  int g = blockIdx.x * 256 + threadIdx.x;
  int bth = g >> 3, j0 = (g & 7) * 8;
  int b = bth >> 15, t = (bth >> 4) & 2047, h = bth & 15;
  int mlidx = (((b << 4) | h) << 11) | t;
  float2 v0 = ml[mlidx];
  float2 v1 = ml[NB * NHEAD * TSEQ + mlidx];
  float M = fmaxf(v0.x, v1.x);
  float a0 = exp2fast(v0.x - M), a1 = exp2fast(v1.x - M);
  float rd = __fdividef(1.f, __builtin_fmaf(v0.y, a0, v1.y * a1));
  float s0 = a0 * rd, s1 = a1 * rd;
  size_t base = (size_t)bth * 64 + j0;
  s16x8 x0 = *(const s16x8*)(o0 + base);
  s16x8 x1 = *(const s16x8*)(o1 + base);
  s16x8 out;
#pragma unroll
  for (int j = 0; j < 8; ++j) {
    float f = __builtin_fmaf(bf2f((u16)x0[j]), s0, bf2f((u16)x1[j]) * s1);
    out[j] = (short)f2bf(f);
  }
  *(s16x8*)(aout + base) = out;
}

extern "C" void kernel_launch(void* const* d_in, const int* in_sizes, int n_in,
                              void* d_out, int out_size, void* d_ws, size_t ws_size,
                              hipStream_t stream) {
  const float* query = (const float*)d_in[0];
  const float* key_  = (const float*)d_in[1];
  const float* value = (const float*)d_in[2];
  const float* frac  = (const float*)d_in[3];
  const float* Wq    = (const float*)d_in[4];
  const float* bq    = (const float*)d_in[5];
  const float* Wk    = (const float*)d_in[6];
  const float* bk    = (const float*)d_in[7];
  const float* Wv    = (const float*)d_in[8];
  const float* bv    = (const float*)d_in[9];
  const float* abias = (const float*)d_in[10];
  const float* Wo    = (const float*)d_in[11];
  const float* bo    = (const float*)d_in[12];

  char* ws = (char*)d_ws;
  size_t off = 0;
  auto alloc = [&](size_t bytes) { char* p = ws + off; off += (bytes + 255) & ~255ULL; return p; };
  const size_t XB = (size_t)MROWS * D_MODEL * 2;
  const size_t WB = (size_t)D_MODEL * D_MODEL * 2;
  u16* qb  = (u16*)alloc(XB);
  u16* kb  = (u16*)alloc(XB);
  u16* vb  = (u16*)alloc(XB);
  u16* Wqb = (u16*)alloc(WB);
  u16* Wkb = (u16*)alloc(WB);
  u16* Wvb = (u16*)alloc(WB);
  u16* Wob = (u16*)alloc(WB);
  float* bsum = (float*)alloc(256);
  u16* Qp  = (u16*)alloc(XB);
  u16* Kp  = (u16*)alloc(XB);
  u16* Vtp = (u16*)alloc(XB);
  u16* AO  = (u16*)alloc(XB);

  // kv-split partial buffers reuse regions that are dead after gemm_qkv:
  u16* o0 = qb;                 // 8.39 MB
  u16* o1 = kb;                 // 8.39 MB
  float2* ml = (float2*)vb;     // 1 MB used

  cvt_all<<<dim3(16385), dim3(256), 0, stream>>>(query, key_, value, Wq, Wk, Wv, Wo, abias,
                                                 qb, kb, vb, Wqb, Wkb, Wvb, Wob, bsum);

  gemm_qkv<<<dim3(D_MODEL / 128, MROWS / 128, 3), dim3(256), 0, stream>>>(
      qb, kb, vb, Wqb, Wkb, Wvb, bq, bk, bv, Qp, Kp, Vtp);

  attn_kernel<<<dim3(TSEQ / 128, NB * NHEAD, NSPLIT), dim3(512), 0, stream>>>(
      Qp, Kp, Vtp, frac, bsum, o0, o1, ml);

  attn_combine<<<dim3(MROWS * D_MODEL / 8 / 256), dim3(256), 0, stream>>>(o0, o1, ml, AO);

  gemm_out<<<dim3(D_MODEL / 128, MROWS / 64), dim3(256), 0, stream>>>(AO, Wob, bo, (float*)d_out);
}

// Round 8
// 182.278 us; speedup vs baseline: 3.3583x; 3.3583x over previous
//
#include <hip/hip_runtime.h>

typedef short s16x8 __attribute__((ext_vector_type(8)));
typedef float f32x4 __attribute__((ext_vector_type(4)));
typedef unsigned int u32x2 __attribute__((ext_vector_type(2)));
typedef unsigned short u16;
typedef unsigned int u32;

#define D_MODEL 1024
#define NHEAD   16
#define HD      64
#define TSEQ    2048
#define NB      2
#define MROWS   4096   // B*T
#define NSPLIT  2
#define NTILES  (TSEQ / 64 / NSPLIT)   // 16 kv tiles per split

#define LOG2E 1.4426950408889634f
#define QSCALE (0.125f * LOG2E)   // folded into Q projection epilogue

__device__ __forceinline__ u16 f2bf(float f) {
  unsigned u = __builtin_bit_cast(unsigned, f);
  u += 0x7fffu + ((u >> 16) & 1u);
  return (u16)(u >> 16);
}

__device__ __forceinline__ float bf2f(u16 x) {
  return __builtin_bit_cast(float, (u32)x << 16);
}

__device__ __forceinline__ u32 cvtpk(float lo, float hi) {
  u32 r;
  asm("v_cvt_pk_bf16_f32 %0, %1, %2" : "=v"(r) : "v"(lo), "v"(hi));
  return r;
}

__device__ __forceinline__ float exp2fast(float x) {
#if __has_builtin(__builtin_amdgcn_exp2f)
  return __builtin_amdgcn_exp2f(x);
#else
  return exp2f(x);
#endif
}

__device__ __forceinline__ float rcpfast(float x) {
#if __has_builtin(__builtin_amdgcn_rcpf)
  return __builtin_amdgcn_rcpf(x);
#else
  return 1.f / x;
#endif
}

__device__ __forceinline__ void gload16(const void* g, void* l) {
  __builtin_amdgcn_global_load_lds((const __attribute__((address_space(1))) void*)g,
                                   (__attribute__((address_space(3))) void*)l,
                                   16, 0, 0);
}

// ---------------- fused fp32->bf16 converts + bias_sum (one dispatch) ----------------
__global__ void cvt_all(const float* __restrict__ q, const float* __restrict__ k,
                        const float* __restrict__ v, const float* __restrict__ wq,
                        const float* __restrict__ wk, const float* __restrict__ wv,
                        const float* __restrict__ wo, const float* __restrict__ ab,
                        u16* qb, u16* kb, u16* vb, u16* wqb, u16* wkb, u16* wvb, u16* wob,
                        float* bsum) {
  if (blockIdx.x == 16384) {
    if (threadIdx.x < 64) {
      float s = ab[threadIdx.x];
#pragma unroll
      for (int m = 32; m >= 1; m >>= 1) s += __shfl_xor(s, m);
      if (threadIdx.x == 0) bsum[0] = s * 0.125f * LOG2E;  // pre-fold scale*log2e
    }
    return;
  }
  int i = blockIdx.x * 256 + threadIdx.x;   // float4 index
  const float* src; u16* dst; int off;
  if (i < 3 * 1048576) {
    int t = i >> 20; off = i & 1048575;
    src = (t == 0) ? q : (t == 1) ? k : v;
    dst = (t == 0) ? qb : (t == 1) ? kb : vb;
  } else {
    int j = i - 3 * 1048576;
    int t = j >> 18; off = j & 262143;
    src = (t == 0) ? wq : (t == 1) ? wk : (t == 2) ? wv : wo;
    dst = (t == 0) ? wqb : (t == 1) ? wkb : (t == 2) ? wvb : wob;
  }
  float4 x = ((const float4*)src)[off];
  ushort4 o;
  o.x = f2bf(x.x); o.y = f2bf(x.y); o.z = f2bf(x.z); o.w = f2bf(x.w);
  ((ushort4*)dst)[off] = o;
}

// ---------------- double-buffered GEMM core: C = (A*Bt^T + bias)*oscale ----------------
// MODE 0: out bf16 (B,H,T,Dh);  MODE 1: out bf16 (B,H,Dh,T) via swapped-operand MFMA
// (acc holds C^T so the t-major stores coalesce);  MODE 2: out fp32 row-major.
template <int BM, int BN, int WN, int MODE>
__device__ __forceinline__ void gemm_core(const u16* __restrict__ A, const u16* __restrict__ Bt,
                                          const float* __restrict__ bias, void* __restrict__ out,
                                          float oscale, u16* lds) {
  constexpr int K = 1024, N = 1024;
  constexpr int WM = 4 / WN;
  constexpr int WTM = BM / WM, WTN = BN / WN;
  constexpr int MR = WTM / 16, NR = WTN / 16;
  constexpr int ASZ = BM * 32, BSZ = BN * 32;
  constexpr int AISS = ASZ / 2048, BISS = BSZ / 2048;
  u16* lA = lds;
  u16* lB = lds + 2 * ASZ;

  const int tid = threadIdx.x;
  const int wid = tid >> 6, lane = tid & 63;
  const int l15 = lane & 15, lgp = lane >> 4;
  const int wr = wid / WN, wc = wid % WN;
  const int m0 = blockIdx.y * BM, n0 = blockIdx.x * BN;

  const u16* gA[AISS];
  const u16* gB[BISS];
#pragma unroll
  for (int i = 0; i < AISS; ++i) {
    int tp = i * 256 + tid, row = tp % BM, kc = tp / BM;
    gA[i] = A + (size_t)(m0 + row) * K + kc * 8;
  }
#pragma unroll
  for (int i = 0; i < BISS; ++i) {
    int tp = i * 256 + tid, row = tp % BN, kc = tp / BN;
    gB[i] = Bt + (size_t)(n0 + row) * K + kc * 8;
  }

  f32x4 acc[MR][NR];
#pragma unroll
  for (int m = 0; m < MR; ++m)
#pragma unroll
    for (int n = 0; n < NR; ++n) acc[m][n] = (f32x4){0.f, 0.f, 0.f, 0.f};

  auto stage = [&](int buf, int k0) {
#pragma unroll
    for (int i = 0; i < AISS; ++i)
      gload16(gA[i] + k0, lA + buf * ASZ + (i * 256 + tid) * 8);
#pragma unroll
    for (int i = 0; i < BISS; ++i)
      gload16(gB[i] + k0, lB + buf * BSZ + (i * 256 + tid) * 8);
  };

  int cur = 0;
  stage(0, 0);
  __syncthreads();
  for (int k0 = 0; k0 < K; k0 += 32) {
    if (k0 + 32 < K) stage(cur ^ 1, k0 + 32);
    const u16* a = lA + cur * ASZ;
    const u16* b = lB + cur * BSZ;
    s16x8 af[MR], bf[NR];
#pragma unroll
    for (int m = 0; m < MR; ++m)
      af[m] = *(const s16x8*)(a + lgp * BM * 8 + (wr * WTM + m * 16 + l15) * 8);
#pragma unroll
    for (int n = 0; n < NR; ++n)
      bf[n] = *(const s16x8*)(b + lgp * BN * 8 + (wc * WTN + n * 16 + l15) * 8);
    __builtin_amdgcn_s_setprio(1);
#pragma unroll
    for (int m = 0; m < MR; ++m)
#pragma unroll
      for (int n = 0; n < NR; ++n) {
        if (MODE == 1)
          acc[m][n] = __builtin_amdgcn_mfma_f32_16x16x32_bf16(bf[n], af[m], acc[m][n], 0, 0, 0);
        else
          acc[m][n] = __builtin_amdgcn_mfma_f32_16x16x32_bf16(af[m], bf[n], acc[m][n], 0, 0, 0);
      }
    __builtin_amdgcn_s_setprio(0);
    __syncthreads();
    cur ^= 1;
  }

  if (MODE == 1) {
    // acc[m][n] = C^T tile: row (lgp*4+r) = n-dir (dmodel-out), col (l15) = m-dir (token)
    float4 bvv4[NR];
#pragma unroll
    for (int n = 0; n < NR; ++n)
      bvv4[n] = *(const float4*)(bias + n0 + wc * WTN + n * 16 + lgp * 4);
#pragma unroll
    for (int m = 0; m < MR; ++m) {
      int m_abs = m0 + wr * WTM + m * 16 + l15;
      int bb = m_abs >> 11, t = m_abs & 2047;
#pragma unroll
      for (int n = 0; n < NR; ++n) {
#pragma unroll
        for (int r = 0; r < 4; ++r) {
          int n_abs = n0 + wc * WTN + n * 16 + lgp * 4 + r;
          int h = n_abs >> 6, d = n_abs & 63;
          float vv = (acc[m][n][r] + ((const float*)&bvv4[n])[r]) * oscale;
          ((u16*)out)[(((size_t)((bb * NHEAD + h) * HD + d)) << 11) + t] = f2bf(vv);
        }
      }
    }
  } else {
    float bvv[NR];
#pragma unroll
    for (int n = 0; n < NR; ++n) bvv[n] = bias[n0 + wc * WTN + n * 16 + l15];
#pragma unroll
    for (int m = 0; m < MR; ++m) {
      int rowb = m0 + wr * WTM + m * 16 + lgp * 4;
#pragma unroll
      for (int n = 0; n < NR; ++n) {
        int col = n0 + wc * WTN + n * 16 + l15;
#pragma unroll
        for (int r = 0; r < 4; ++r) {
          int row = rowb + r;
          float vv = (acc[m][n][r] + bvv[n]) * oscale;
          if (MODE == 2) {
            ((float*)out)[(size_t)row * N + col] = vv;
          } else {
            int b = row >> 11, t = row & 2047;
            int h = col >> 6, d = col & 63;
            ((u16*)out)[(((size_t)(b * NHEAD + h) * TSEQ + t) << 6) + d] = f2bf(vv);
          }
        }
      }
    }
  }
}

__global__ __launch_bounds__(256) void gemm_qkv(const u16* __restrict__ qb, const u16* __restrict__ kb,
                                                const u16* __restrict__ vb,
                                                const u16* __restrict__ Wqb, const u16* __restrict__ Wkb,
                                                const u16* __restrict__ Wvb,
                                                const float* __restrict__ bq, const float* __restrict__ bk,
                                                const float* __restrict__ bv,
                                                u16* Qp, u16* Kp, u16* Vtp) {
  __shared__ __align__(16) u16 lds[2 * 128 * 32 * 2];   // 32 KB
  int z = blockIdx.z;
  if (z == 0)
    gemm_core<128, 128, 2, 0>(qb, Wqb, bq, Qp, QSCALE, lds);
  else if (z == 1)
    gemm_core<128, 128, 2, 0>(kb, Wkb, bk, Kp, 1.0f, lds);
  else
    gemm_core<128, 128, 2, 1>(vb, Wvb, bv, Vtp, 1.0f, lds);
}

__global__ __launch_bounds__(256) void gemm_out(const u16* __restrict__ A, const u16* __restrict__ Bt,
                                                const float* __restrict__ bias, float* __restrict__ out) {
  __shared__ __align__(16) u16 lds[2 * 64 * 32 + 2 * 128 * 32];   // 24 KB
  gemm_core<64, 128, 4, 2>(A, Bt, bias, out, 1.0f, lds);
}

// ---------------- flash attention, kv-split x2, 8 waves/block, 40KB LDS ----------------
// grid: (T/128, B*H, NSPLIT), block 512 = 8 waves. Wave w owns 16 q rows [bx*128+w*16, +16).
// K single-buffered (8KB), V double (16KB), per-wave plds (16KB).
// NOTE: launch_bounds min-waves/EU MUST stay 4 (128-VGPR budget). 8 forces a 64-VGPR cap ->
// the ~104 live regs spill to scratch -> 1 GB/dispatch scratch traffic, 6x slowdown (R7).
//   read K-frags -> sync1 -> stage K(t+1),V(t+1) -> QK -> softmax -> PV(vbuf[cur]) -> sync2
// Outputs UNNORMALIZED partial O (bf16) + per-row (m2, lsum) for the combine pass.
__global__ __launch_bounds__(512, 4) void attn_kernel(const u16* __restrict__ Qp,
                                                      const u16* __restrict__ Kp,
                                                      const u16* __restrict__ Vt,
                                                      const float* __restrict__ frac,
                                                      const float* __restrict__ bsum,
                                                      u16* __restrict__ o0,
                                                      u16* __restrict__ o1,
                                                      float2* __restrict__ ml) {
  __shared__ __align__(16) u16 kbuf[64 * 64];       // 8 KB (single-buffered)
  __shared__ __align__(16) u16 vbuf[2][64 * 64];    // 16 KB
  __shared__ __align__(16) u16 plds[8][16 * 64];    // 16 KB
  const int tid = threadIdx.x, wid = tid >> 6, lane = tid & 63;
  const int l15 = lane & 15, lgp = lane >> 4;
  const int bh = blockIdx.y, b = bh >> 4, h = bh & 15;
  const int z = blockIdx.z;
  const int kvbase = z * (TSEQ / NSPLIT);
  u16* opart = z ? o1 : o0;
  float2* mlz = ml + z * (NB * NHEAD * TSEQ);
  const u16* Qh = Qp + (size_t)bh * TSEQ * HD;
  const u16* Kh = Kp + (size_t)bh * TSEQ * HD;
  const u16* Vh = Vt + (size_t)bh * HD * TSEQ;
  const float* fb = frac + b * TSEQ;
  const float bs = bsum[0];                    // bias_sum * scale * log2e (pre-folded)
  const float THR2 = 24.0f;
  const int q0 = blockIdx.x * 128 + wid * 16;

  // staging lane constants (pre-swizzled global source, rule #21)
  const int srow = lane >> 3;                  // wave covers rows wid*8 .. wid*8+7
  const int sg8 = ((lane & 7) ^ srow) * 8;     // swizzled col8 * 8 (u16 units)
  const int rbase = wid * 8 + srow;

  // frag-read offsets (u16 units)
  const int ofs0 = l15 * 64 + ((lgp ^ (l15 & 7)) * 8);
  const int ofs1 = l15 * 64 + (((4 + lgp) ^ (l15 & 7)) * 8);

  // Q fragments (B-operand: lane l15 = q col, lgp*8 = dh slice)
  s16x8 qf[2];
#pragma unroll
  for (int ks = 0; ks < 2; ++ks)
    qf[ks] = *(const s16x8*)(Qh + (size_t)(q0 + l15) * HD + ks * 32 + lgp * 8);

  const float fi = fb[q0 + l15];
  const float nbfi = -bs * fi;
  float m2run = -1e30f;
  float lsum = 0.f;
  f32x4 o[4];
#pragma unroll
  for (int nd = 0; nd < 4; ++nd) o[nd] = (f32x4){0.f, 0.f, 0.f, 0.f};

  auto stageK = [&](int t) {
    int kv0s = kvbase + t * 64;
    gload16(Kh + (size_t)(kv0s + rbase) * HD + sg8, &kbuf[wid * 512]);
  };
  auto stageV = [&](int buf, int t) {
    int kv0s = kvbase + t * 64;
    gload16(Vh + (size_t)rbase * TSEQ + kv0s + sg8, &vbuf[buf][wid * 512]);
  };

  int cur = 0;
  stageK(0);
  stageV(0, 0);
  __syncthreads();

  for (int t = 0; t < NTILES; ++t) {
    // ---- grab K fragments from kbuf into registers
    s16x8 kf[4][2];
#pragma unroll
    for (int n = 0; n < 4; ++n) {
      kf[n][0] = *(const s16x8*)(&kbuf[0] + n * 1024 + ofs0);
      kf[n][1] = *(const s16x8*)(&kbuf[0] + n * 1024 + ofs1);
    }
    float4 fj4[4];
#pragma unroll
    for (int n = 0; n < 4; ++n)
      fj4[n] = *(const float4*)(fb + kvbase + t * 64 + n * 16 + lgp * 4);

    __syncthreads();   // sync1: all waves done reading kbuf
    if (t + 1 < NTILES) { stageK(t + 1); stageV(cur ^ 1, t + 1); }

    // ---- QK^T (swapped): s[n][r] = S_log2[kv][q0+l15]
    f32x4 s[4];
    __builtin_amdgcn_s_setprio(1);
#pragma unroll
    for (int n = 0; n < 4; ++n) {
      f32x4 a = (f32x4){0.f, 0.f, 0.f, 0.f};
      a = __builtin_amdgcn_mfma_f32_16x16x32_bf16(kf[n][0], qf[0], a, 0, 0, 0);
      a = __builtin_amdgcn_mfma_f32_16x16x32_bf16(kf[n][1], qf[1], a, 0, 0, 0);
      s[n] = a;
    }
    __builtin_amdgcn_s_setprio(0);

    // ---- logits (log2 domain): l2 = s + bs*(fj-fi)/(fi*fj+eps)
    float pmax = -1e30f;
#pragma unroll
    for (int n = 0; n < 4; ++n) {
#pragma unroll
      for (int r = 0; r < 4; ++r) {
        float fj = (r == 0) ? fj4[n].x : (r == 1) ? fj4[n].y : (r == 2) ? fj4[n].z : fj4[n].w;
        float num = __builtin_fmaf(bs, fj, nbfi);
        float den = __builtin_fmaf(fi, fj, 1e-8f);
        float l2 = __builtin_fmaf(num, rcpfast(den), s[n][r]);
        s[n][r] = l2;
        pmax = fmaxf(pmax, l2);
      }
    }

    // ---- rare rescale (speculative defer-max)
    if (__any((pmax - m2run) > THR2)) {
      float tm = fmaxf(pmax, __shfl_xor(pmax, 16));
      tm = fmaxf(tm, __shfl_xor(tm, 32));
      float m2n = fmaxf(m2run, tm);
      float alpha = exp2fast(m2run - m2n);
      lsum *= alpha;
      m2run = m2n;
      float af[4];
#pragma unroll
      for (int r = 0; r < 4; ++r) af[r] = __shfl(alpha, lgp * 4 + r);
#pragma unroll
      for (int nd = 0; nd < 4; ++nd)
#pragma unroll
        for (int r = 0; r < 4; ++r) o[nd][r] *= af[r];
    }

    // ---- P = exp2(l2 - m2run), pack bf16, partial row-sum
    u32 w[4][2];
    {
      float ps = 0.f;
#pragma unroll
      for (int n = 0; n < 4; ++n) {
#pragma unroll
        for (int s2 = 0; s2 < 2; ++s2) {
          float p0 = exp2fast(s[n][2 * s2 + 0] - m2run);
          float p1 = exp2fast(s[n][2 * s2 + 1] - m2run);
          ps += p0 + p1;
          w[n][s2] = cvtpk(p0, p1);
        }
      }
      lsum += ps;
    }

    // ---- P -> per-wave LDS (swizzled) -> A-operand frags
    u16* pw = &plds[wid][0];
#pragma unroll
    for (int n = 0; n < 4; ++n) {
      int idx = l15 * 64 + ((n * 16 + lgp * 4) ^ ((l15 & 7) << 3));
      *(u32x2*)(pw + idx) = (u32x2){w[n][0], w[n][1]};
    }
    s16x8 pf[2];
#pragma unroll
    for (int ks = 0; ks < 2; ++ks) {
      int idx = l15 * 64 + ((ks * 32 + lgp * 8) ^ ((l15 & 7) << 3));
      pf[ks] = *(const s16x8*)(pw + idx);
    }

    // ---- PV: o[nd] += P * V
    const u16* vbp = &vbuf[cur][0];
    __builtin_amdgcn_s_setprio(1);
#pragma unroll
    for (int nd = 0; nd < 4; ++nd) {
      s16x8 vf0 = *(const s16x8*)(vbp + nd * 1024 + ofs0);
      s16x8 vf1 = *(const s16x8*)(vbp + nd * 1024 + ofs1);
      o[nd] = __builtin_amdgcn_mfma_f32_16x16x32_bf16(pf[0], vf0, o[nd], 0, 0, 0);
      o[nd] = __builtin_amdgcn_mfma_f32_16x16x32_bf16(pf[1], vf1, o[nd], 0, 0, 0);
    }
    __builtin_amdgcn_s_setprio(0);

    __syncthreads();   // sync2: drains staged gloads, protects vbuf/kbuf
    cur ^= 1;
  }

  // ---- epilogue: reduce lsum across lgp, store (m,l) + unnormalized partial O
  {
    float l = lsum;
    l += __shfl_xor(l, 16);
    l += __shfl_xor(l, 32);
    if (lgp == 0)
      mlz[(bh << 11) + q0 + l15] = make_float2(m2run, l);
#pragma unroll
    for (int nd = 0; nd < 4; ++nd)
#pragma unroll
      for (int r = 0; r < 4; ++r) {
        int q = q0 + lgp * 4 + r;
        opart[((size_t)(b * TSEQ + q)) * D_MODEL + h * HD + nd * 16 + l15] = f2bf(o[nd][r]);
      }
  }
}

// ---------------- combine the 2 kv-splits ----------------
__global__ __launch_bounds__(256) void attn_combine(const u16* __restrict__ o0,
                                                    const u16* __restrict__ o1,
                                                    const float2* __restrict__ ml,
                                                    u16* __restrict__ aout) {
  int g = blockIdx.x * 256 + threadIdx.x;
  int bth = g >> 3, j0 = (g & 7) * 8;
  int b = bth >> 15, t = (bth >> 4) & 2047, h = bth & 15;
  int mlidx = (((b << 4) | h) << 11) | t;
  float2 v0 = ml[mlidx];
  float2 v1 = ml[NB * NHEAD * TSEQ + mlidx];
  float M = fmaxf(v0.x, v1.x);
  float a0 = exp2fast(v0.x - M), a1 = exp2fast(v1.x - M);
  float rd = __fdividef(1.f, __builtin_fmaf(v0.y, a0, v1.y * a1));
  float s0 = a0 * rd, s1 = a1 * rd;
  size_t base = (size_t)bth * 64 + j0;
  s16x8 x0 = *(const s16x8*)(o0 + base);
  s16x8 x1 = *(const s16x8*)(o1 + base);
  s16x8 out;
#pragma unroll
  for (int j = 0; j < 8; ++j) {
    float f = __builtin_fmaf(bf2f((u16)x0[j]), s0, bf2f((u16)x1[j]) * s1);
    out[j] = (short)f2bf(f);
  }
  *(s16x8*)(aout + base) = out;
}

extern "C" void kernel_launch(void* const* d_in, const int* in_sizes, int n_in,
                              void* d_out, int out_size, void* d_ws, size_t ws_size,
                              hipStream_t stream) {
  const float* query = (const float*)d_in[0];
  const float* key_  = (const float*)d_in[1];
  const float* value = (const float*)d_in[2];
  const float* frac  = (const float*)d_in[3];
  const float* Wq    = (const float*)d_in[4];
  const float* bq    = (const float*)d_in[5];
  const float* Wk    = (const float*)d_in[6];
  const float* bk    = (const float*)d_in[7];
  const float* Wv    = (const float*)d_in[8];
  const float* bv    = (const float*)d_in[9];
  const float* abias = (const float*)d_in[10];
  const float* Wo    = (const float*)d_in[11];
  const float* bo    = (const float*)d_in[12];

  char* ws = (char*)d_ws;
  size_t off = 0;
  auto alloc = [&](size_t bytes) { char* p = ws + off; off += (bytes + 255) & ~255ULL; return p; };
  const size_t XB = (size_t)MROWS * D_MODEL * 2;
  const size_t WB = (size_t)D_MODEL * D_MODEL * 2;
  u16* qb  = (u16*)alloc(XB);
  u16* kb  = (u16*)alloc(XB);
  u16* vb  = (u16*)alloc(XB);
  u16* Wqb = (u16*)alloc(WB);
  u16* Wkb = (u16*)alloc(WB);
  u16* Wvb = (u16*)alloc(WB);
  u16* Wob = (u16*)alloc(WB);
  float* bsum = (float*)alloc(256);
  u16* Qp  = (u16*)alloc(XB);
  u16* Kp  = (u16*)alloc(XB);
  u16* Vtp = (u16*)alloc(XB);
  u16* AO  = (u16*)alloc(XB);

  // kv-split partial buffers reuse regions that are dead after gemm_qkv:
  u16* o0 = qb;                 // 8.39 MB
  u16* o1 = kb;                 // 8.39 MB
  float2* ml = (float2*)vb;     // 1 MB used

  cvt_all<<<dim3(16385), dim3(256), 0, stream>>>(query, key_, value, Wq, Wk, Wv, Wo, abias,
                                                 qb, kb, vb, Wqb, Wkb, Wvb, Wob, bsum);

  gemm_qkv<<<dim3(D_MODEL / 128, MROWS / 128, 3), dim3(256), 0, stream>>>(
      qb, kb, vb, Wqb, Wkb, Wvb, bq, bk, bv, Qp, Kp, Vtp);

  attn_kernel<<<dim3(TSEQ / 128, NB * NHEAD, NSPLIT), dim3(512), 0, stream>>>(
      Qp, Kp, Vtp, frac, bsum, o0, o1, ml);

  attn_combine<<<dim3(MROWS * D_MODEL / 8 / 256), dim3(256), 0, stream>>>(o0, o1, ml, AO);

  gemm_out<<<dim3(D_MODEL / 128, MROWS / 64), dim3(256), 0, stream>>>(AO, Wob, bo, (float*)d_out);
}

// Round 9
// 181.712 us; speedup vs baseline: 3.3688x; 1.0031x over previous
//
#include <hip/hip_runtime.h>

typedef short s16x8 __attribute__((ext_vector_type(8)));
typedef float f32x4 __attribute__((ext_vector_type(4)));
typedef float f32x16 __attribute__((ext_vector_type(16)));
typedef unsigned int u32x2 __attribute__((ext_vector_type(2)));
typedef unsigned int u32x4 __attribute__((ext_vector_type(4)));
typedef unsigned short u16;
typedef unsigned int u32;

#define D_MODEL 1024
#define NHEAD   16
#define HD      64
#define TSEQ    2048
#define NB      2
#define MROWS   4096   // B*T
#define NSPLIT  2
#define NTILES  (TSEQ / 64 / NSPLIT)   // 16 kv tiles per split

#define LOG2E 1.4426950408889634f
#define QSCALE (0.125f * LOG2E)   // folded into Q projection epilogue

__device__ __forceinline__ u16 f2bf(float f) {
  unsigned u = __builtin_bit_cast(unsigned, f);
  u += 0x7fffu + ((u >> 16) & 1u);
  return (u16)(u >> 16);
}

__device__ __forceinline__ float bf2f(u16 x) {
  return __builtin_bit_cast(float, (u32)x << 16);
}

__device__ __forceinline__ u32 cvtpk(float lo, float hi) {
  u32 r;
  asm("v_cvt_pk_bf16_f32 %0, %1, %2" : "=v"(r) : "v"(lo), "v"(hi));
  return r;
}

__device__ __forceinline__ float exp2fast(float x) {
#if __has_builtin(__builtin_amdgcn_exp2f)
  return __builtin_amdgcn_exp2f(x);
#else
  return exp2f(x);
#endif
}

__device__ __forceinline__ float rcpfast(float x) {
#if __has_builtin(__builtin_amdgcn_rcpf)
  return __builtin_amdgcn_rcpf(x);
#else
  return 1.f / x;
#endif
}

__device__ __forceinline__ void gload16(const void* g, void* l) {
  __builtin_amdgcn_global_load_lds((const __attribute__((address_space(1))) void*)g,
                                   (__attribute__((address_space(3))) void*)l,
                                   16, 0, 0);
}

// ---------------- fused fp32->bf16 converts + bias_sum (one dispatch) ----------------
__global__ void cvt_all(const float* __restrict__ q, const float* __restrict__ k,
                        const float* __restrict__ v, const float* __restrict__ wq,
                        const float* __restrict__ wk, const float* __restrict__ wv,
                        const float* __restrict__ wo, const float* __restrict__ ab,
                        u16* qb, u16* kb, u16* vb, u16* wqb, u16* wkb, u16* wvb, u16* wob,
                        float* bsum) {
  if (blockIdx.x == 16384) {
    if (threadIdx.x < 64) {
      float s = ab[threadIdx.x];
#pragma unroll
      for (int m = 32; m >= 1; m >>= 1) s += __shfl_xor(s, m);
      if (threadIdx.x == 0) bsum[0] = s * 0.125f * LOG2E;  // pre-fold scale*log2e
    }
    return;
  }
  int i = blockIdx.x * 256 + threadIdx.x;   // float4 index
  const float* src; u16* dst; int off;
  if (i < 3 * 1048576) {
    int t = i >> 20; off = i & 1048575;
    src = (t == 0) ? q : (t == 1) ? k : v;
    dst = (t == 0) ? qb : (t == 1) ? kb : vb;
  } else {
    int j = i - 3 * 1048576;
    int t = j >> 18; off = j & 262143;
    src = (t == 0) ? wq : (t == 1) ? wk : (t == 2) ? wv : wo;
    dst = (t == 0) ? wqb : (t == 1) ? wkb : (t == 2) ? wvb : wob;
  }
  float4 x = ((const float4*)src)[off];
  ushort4 o;
  o.x = f2bf(x.x); o.y = f2bf(x.y); o.z = f2bf(x.z); o.w = f2bf(x.w);
  ((ushort4*)dst)[off] = o;
}

// ---------------- double-buffered GEMM core: C = (A*Bt^T + bias)*oscale ----------------
// MODE 0: out bf16 (B,H,T,Dh);  MODE 1: out bf16 (B,H,Dh,T) via swapped-operand MFMA
// (acc holds C^T so the t-major stores coalesce);  MODE 2: out fp32 row-major.
template <int BM, int BN, int WN, int MODE>
__device__ __forceinline__ void gemm_core(const u16* __restrict__ A, const u16* __restrict__ Bt,
                                          const float* __restrict__ bias, void* __restrict__ out,
                                          float oscale, u16* lds) {
  constexpr int K = 1024, N = 1024;
  constexpr int WM = 4 / WN;
  constexpr int WTM = BM / WM, WTN = BN / WN;
  constexpr int MR = WTM / 16, NR = WTN / 16;
  constexpr int ASZ = BM * 32, BSZ = BN * 32;
  constexpr int AISS = ASZ / 2048, BISS = BSZ / 2048;
  u16* lA = lds;
  u16* lB = lds + 2 * ASZ;

  const int tid = threadIdx.x;
  const int wid = tid >> 6, lane = tid & 63;
  const int l15 = lane & 15, lgp = lane >> 4;
  const int wr = wid / WN, wc = wid % WN;
  const int m0 = blockIdx.y * BM, n0 = blockIdx.x * BN;

  const u16* gA[AISS];
  const u16* gB[BISS];
#pragma unroll
  for (int i = 0; i < AISS; ++i) {
    int tp = i * 256 + tid, row = tp % BM, kc = tp / BM;
    gA[i] = A + (size_t)(m0 + row) * K + kc * 8;
  }
#pragma unroll
  for (int i = 0; i < BISS; ++i) {
    int tp = i * 256 + tid, row = tp % BN, kc = tp / BN;
    gB[i] = Bt + (size_t)(n0 + row) * K + kc * 8;
  }

  f32x4 acc[MR][NR];
#pragma unroll
  for (int m = 0; m < MR; ++m)
#pragma unroll
    for (int n = 0; n < NR; ++n) acc[m][n] = (f32x4){0.f, 0.f, 0.f, 0.f};

  auto stage = [&](int buf, int k0) {
#pragma unroll
    for (int i = 0; i < AISS; ++i)
      gload16(gA[i] + k0, lA + buf * ASZ + (i * 256 + tid) * 8);
#pragma unroll
    for (int i = 0; i < BISS; ++i)
      gload16(gB[i] + k0, lB + buf * BSZ + (i * 256 + tid) * 8);
  };

  int cur = 0;
  stage(0, 0);
  __syncthreads();
  for (int k0 = 0; k0 < K; k0 += 32) {
    if (k0 + 32 < K) stage(cur ^ 1, k0 + 32);
    const u16* a = lA + cur * ASZ;
    const u16* b = lB + cur * BSZ;
    s16x8 af[MR], bf[NR];
#pragma unroll
    for (int m = 0; m < MR; ++m)
      af[m] = *(const s16x8*)(a + lgp * BM * 8 + (wr * WTM + m * 16 + l15) * 8);
#pragma unroll
    for (int n = 0; n < NR; ++n)
      bf[n] = *(const s16x8*)(b + lgp * BN * 8 + (wc * WTN + n * 16 + l15) * 8);
    __builtin_amdgcn_s_setprio(1);
#pragma unroll
    for (int m = 0; m < MR; ++m)
#pragma unroll
      for (int n = 0; n < NR; ++n) {
        if (MODE == 1)
          acc[m][n] = __builtin_amdgcn_mfma_f32_16x16x32_bf16(bf[n], af[m], acc[m][n], 0, 0, 0);
        else
          acc[m][n] = __builtin_amdgcn_mfma_f32_16x16x32_bf16(af[m], bf[n], acc[m][n], 0, 0, 0);
      }
    __builtin_amdgcn_s_setprio(0);
    __syncthreads();
    cur ^= 1;
  }

  if (MODE == 1) {
    float4 bvv4[NR];
#pragma unroll
    for (int n = 0; n < NR; ++n)
      bvv4[n] = *(const float4*)(bias + n0 + wc * WTN + n * 16 + lgp * 4);
#pragma unroll
    for (int m = 0; m < MR; ++m) {
      int m_abs = m0 + wr * WTM + m * 16 + l15;
      int bb = m_abs >> 11, t = m_abs & 2047;
#pragma unroll
      for (int n = 0; n < NR; ++n) {
#pragma unroll
        for (int r = 0; r < 4; ++r) {
          int n_abs = n0 + wc * WTN + n * 16 + lgp * 4 + r;
          int h = n_abs >> 6, d = n_abs & 63;
          float vv = (acc[m][n][r] + ((const float*)&bvv4[n])[r]) * oscale;
          ((u16*)out)[(((size_t)((bb * NHEAD + h) * HD + d)) << 11) + t] = f2bf(vv);
        }
      }
    }
  } else {
    float bvv[NR];
#pragma unroll
    for (int n = 0; n < NR; ++n) bvv[n] = bias[n0 + wc * WTN + n * 16 + l15];
#pragma unroll
    for (int m = 0; m < MR; ++m) {
      int rowb = m0 + wr * WTM + m * 16 + lgp * 4;
#pragma unroll
      for (int n = 0; n < NR; ++n) {
        int col = n0 + wc * WTN + n * 16 + l15;
#pragma unroll
        for (int r = 0; r < 4; ++r) {
          int row = rowb + r;
          float vv = (acc[m][n][r] + bvv[n]) * oscale;
          if (MODE == 2) {
            ((float*)out)[(size_t)row * N + col] = vv;
          } else {
            int b = row >> 11, t = row & 2047;
            int h = col >> 6, d = col & 63;
            ((u16*)out)[(((size_t)(b * NHEAD + h) * TSEQ + t) << 6) + d] = f2bf(vv);
          }
        }
      }
    }
  }
}

__global__ __launch_bounds__(256) void gemm_qkv(const u16* __restrict__ qb, const u16* __restrict__ kb,
                                                const u16* __restrict__ vb,
                                                const u16* __restrict__ Wqb, const u16* __restrict__ Wkb,
                                                const u16* __restrict__ Wvb,
                                                const float* __restrict__ bq, const float* __restrict__ bk,
                                                const float* __restrict__ bv,
                                                u16* Qp, u16* Kp, u16* Vtp) {
  __shared__ __align__(16) u16 lds[2 * 128 * 32 * 2];   // 32 KB
  int z = blockIdx.z;
  if (z == 0)
    gemm_core<128, 128, 2, 0>(qb, Wqb, bq, Qp, QSCALE, lds);
  else if (z == 1)
    gemm_core<128, 128, 2, 0>(kb, Wkb, bk, Kp, 1.0f, lds);
  else
    gemm_core<128, 128, 2, 1>(vb, Wvb, bv, Vtp, 1.0f, lds);
}

__global__ __launch_bounds__(256) void gemm_out(const u16* __restrict__ A, const u16* __restrict__ Bt,
                                                const float* __restrict__ bias, float* __restrict__ out) {
  __shared__ __align__(16) u16 lds[2 * 64 * 32 + 2 * 128 * 32];   // 24 KB
  gemm_core<64, 128, 4, 2>(A, Bt, bias, out, 1.0f, lds);
}

// ---------------- flash attention: 32x32 MFMA, in-register P, kv-split x2 ----------------
// grid: (T/128, B*H, NSPLIT), block 256 = 4 waves. Wave w owns 32 q rows [bx*128+w*32, +32).
// LDS 24KB: kbuf 8KB single-buffered, vbuf 2x8KB. No P LDS (permlane assembly).
// Layouts (mfma_f32_32x32x16_bf16):
//   A: row = lane&31, k = (lane>>5)*8 + j     B: col = lane&31, k = (lane>>5)*8 + j
//   C/D: col = lane&31, row = (reg&3) + 8*(reg>>2) + 4*(lane>>5)
// Swapped QK: S = mfma(K, Q) -> lane holds S[kv = crow(reg,hi)][q = lane&31].
// P->A-frag: lane pair (l, l+32) shares q; v_permlane32_swap_b32 exchanges kv-halves.
__global__ __launch_bounds__(256, 4) void attn_kernel(const u16* __restrict__ Qp,
                                                      const u16* __restrict__ Kp,
                                                      const u16* __restrict__ Vt,
                                                      const float* __restrict__ frac,
                                                      const float* __restrict__ bsum,
                                                      u16* __restrict__ o0,
                                                      u16* __restrict__ o1,
                                                      float2* __restrict__ ml) {
  __shared__ __align__(16) u16 kbuf[64 * 64];       // row = kv, 8 slots; slot s holds col8 s^(row&7)
  __shared__ __align__(16) u16 vbuf[2][64 * 64];    // row = d,  8 slots; same swizzle
  const int tid = threadIdx.x, wid = tid >> 6, lane = tid & 63;
  const int l31 = lane & 31, hi = lane >> 5, hi4 = hi * 4, hi8 = hi * 8;
  const int ksw = l31 & 7;
  const int bh = blockIdx.y, b = bh >> 4, h = bh & 15;
  const int z = blockIdx.z;
  const int kvbase = z * (TSEQ / NSPLIT);
  u16* opart = z ? o1 : o0;
  float2* mlz = ml + z * (NB * NHEAD * TSEQ);
  const u16* Qh = Qp + (size_t)bh * TSEQ * HD;
  const u16* Kh = Kp + (size_t)bh * TSEQ * HD;
  const u16* Vh = Vt + (size_t)bh * HD * TSEQ;
  const float* fb = frac + b * TSEQ;
  const float bs = bsum[0];                    // bias_sum * scale * log2e (pre-folded)
  const float THR2 = 24.0f;
  const int q0w = blockIdx.x * 128 + wid * 32;

  // staging constants: issue i covers 16B-block idx = i*256 + tid: row = idx>>3, slot = idx&7,
  // source col8 = slot ^ (row&7) (pre-swizzled global source, rule #21)
  const int r_0 = tid >> 3, c_0 = ((tid & 7) ^ (r_0 & 7)) * 8;
  const int r_1 = 32 + r_0, c_1 = ((tid & 7) ^ (r_1 & 7)) * 8;
  const u16* Ksrc0 = Kh + (size_t)r_0 * HD + c_0;
  const u16* Ksrc1 = Kh + (size_t)r_1 * HD + c_1;
  const u16* Vsrc0 = Vh + (size_t)r_0 * TSEQ + c_0;
  const u16* Vsrc1 = Vh + (size_t)r_1 * TSEQ + c_1;
  u16* kdst0 = &kbuf[(wid * 64) * 8];
  u16* kdst1 = &kbuf[(256 + wid * 64) * 8];

  // Q fragments (B-operand): lane holds Q[q0w + l31][dc*16 + hi*8 + j]
  s16x8 qf[4];
#pragma unroll
  for (int dc = 0; dc < 4; ++dc)
    qf[dc] = *(const s16x8*)(Qh + (size_t)(q0w + l31) * HD + dc * 16 + hi8);

  const float fi = fb[q0w + l31];
  const float nbfi = -bs * fi;
  float m2run = -1e30f, lsum = 0.f;
  f32x16 o2[2];
#pragma unroll
  for (int dh = 0; dh < 2; ++dh)
#pragma unroll
    for (int i = 0; i < 16; ++i) o2[dh][i] = 0.f;

  auto stage = [&](int buf, int t) {
    int kv0s = kvbase + t * 64;
    gload16(Ksrc0 + (size_t)kv0s * HD, kdst0);
    gload16(Ksrc1 + (size_t)kv0s * HD, kdst1);
    gload16(Vsrc0 + kv0s, &vbuf[buf][(wid * 64) * 8]);
    gload16(Vsrc1 + kv0s, &vbuf[buf][(256 + wid * 64) * 8]);
  };

  int cur = 0;
  stage(0, 0);
  __syncthreads();

  for (int t = 0; t < NTILES; ++t) {
    const int kvt = kvbase + t * 64;

    // ---- QK^T: S2[t2] (32kv x 32q), accumulate over 4 d-chunks
    f32x16 s2[2];
    __builtin_amdgcn_s_setprio(1);
#pragma unroll
    for (int t2 = 0; t2 < 2; ++t2) {
      f32x16 a;
#pragma unroll
      for (int i = 0; i < 16; ++i) a[i] = 0.f;
#pragma unroll
      for (int dc = 0; dc < 4; ++dc) {
        s16x8 kf = *(const s16x8*)(&kbuf[(t2 * 32 + l31) * 64 + (((dc * 2 + hi) ^ ksw) * 8)]);
        a = __builtin_amdgcn_mfma_f32_32x32x16_bf16(kf, qf[dc], a, 0, 0, 0);
      }
      s2[t2] = a;
    }
    __builtin_amdgcn_s_setprio(0);

    __syncthreads();   // sync1: kbuf consumed by all waves
    if (t + 1 < NTILES) stage(cur ^ 1, t + 1);   // K -> kbuf, V -> vbuf[cur^1]

    // ---- logits (log2 domain): kv = kvt + t2*32 + g*8 + hi4 + r4
    float pmax = -1e30f;
#pragma unroll
    for (int t2 = 0; t2 < 2; ++t2) {
#pragma unroll
      for (int g = 0; g < 4; ++g) {
        float4 fj4 = *(const float4*)(fb + kvt + t2 * 32 + g * 8 + hi4);
#pragma unroll
        for (int r4 = 0; r4 < 4; ++r4) {
          float fjv = (r4 == 0) ? fj4.x : (r4 == 1) ? fj4.y : (r4 == 2) ? fj4.z : fj4.w;
          float num = __builtin_fmaf(bs, fjv, nbfi);
          float den = __builtin_fmaf(fi, fjv, 1e-8f);
          float l2 = __builtin_fmaf(num, rcpfast(den), s2[t2][g * 4 + r4]);
          s2[t2][g * 4 + r4] = l2;
          pmax = fmaxf(pmax, l2);
        }
      }
    }

    // ---- rare rescale (speculative defer-max; lane pair (l,l+32) shares q)
    if (__any((pmax - m2run) > THR2)) {
      float tm = fmaxf(pmax, __shfl_xor(pmax, 32));
      float m2n = fmaxf(m2run, tm);
      float alpha = exp2fast(m2run - m2n);
      lsum *= alpha;
      m2run = m2n;
#pragma unroll
      for (int reg = 0; reg < 16; ++reg) {
        float av = __shfl(alpha, (reg & 3) + 8 * (reg >> 2) + hi4);  // alpha lives at lane q
        o2[0][reg] *= av;
        o2[1][reg] *= av;
      }
    }

    // ---- P = exp2(l2 - m), cvt_pk pairs, permlane32_swap -> PV A-frags (no LDS)
    s16x8 pa[4];
#pragma unroll
    for (int t2 = 0; t2 < 2; ++t2) {
      u32 uu[8];
#pragma unroll
      for (int k = 0; k < 8; ++k) {
        float p0 = exp2fast(s2[t2][2 * k + 0] - m2run);
        float p1 = exp2fast(s2[t2][2 * k + 1] - m2run);
        lsum += p0 + p1;
        uu[k] = cvtpk(p0, p1);
      }
      // quarter ks_lo (kv t2*32 + 0..15): words [u0,u1 | swap-partners]
      u32 a0 = uu[0], b0 = uu[2];
      asm("v_permlane32_swap_b32 %0, %1" : "+v"(a0), "+v"(b0));
      u32 a1 = uu[1], b1 = uu[3];
      asm("v_permlane32_swap_b32 %0, %1" : "+v"(a1), "+v"(b1));
      pa[t2 * 2] = __builtin_bit_cast(s16x8, (u32x4){a0, a1, b0, b1});
      // quarter ks_hi (kv t2*32 + 16..31)
      u32 a2 = uu[4], b2 = uu[6];
      asm("v_permlane32_swap_b32 %0, %1" : "+v"(a2), "+v"(b2));
      u32 a3 = uu[5], b3 = uu[7];
      asm("v_permlane32_swap_b32 %0, %1" : "+v"(a3), "+v"(b3));
      pa[t2 * 2 + 1] = __builtin_bit_cast(s16x8, (u32x4){a2, a3, b2, b3});
    }

    // ---- PV: O2[dh](32q x 32d) += P(32q x 16kv) * V(16kv x 32d), 4 kv-quarters
    const u16* vbp = &vbuf[cur][0];
    __builtin_amdgcn_s_setprio(1);
#pragma unroll
    for (int dh = 0; dh < 2; ++dh) {
#pragma unroll
      for (int ks = 0; ks < 4; ++ks) {
        s16x8 vf = *(const s16x8*)(vbp + (dh * 32 + l31) * 64 + (((ks * 2 + hi) ^ ksw) * 8));
        o2[dh] = __builtin_amdgcn_mfma_f32_32x32x16_bf16(pa[ks], vf, o2[dh], 0, 0, 0);
      }
    }
    __builtin_amdgcn_s_setprio(0);

    __syncthreads();   // sync2: staged gloads drained (compiler emits vmcnt(0) before barrier)
    cur ^= 1;
  }

  // ---- epilogue: pair-sum lsum, store (m,l) + unnormalized partial O
  lsum += __shfl_xor(lsum, 32);
  if (hi == 0)
    mlz[(bh << 11) + q0w + l31] = make_float2(m2run, lsum);
#pragma unroll
  for (int dh = 0; dh < 2; ++dh)
#pragma unroll
    for (int reg = 0; reg < 16; ++reg) {
      int q = q0w + (reg & 3) + 8 * (reg >> 2) + hi4;
      opart[((size_t)(b * TSEQ + q)) * D_MODEL + h * HD + dh * 32 + l31] = f2bf(o2[dh][reg]);
    }
}

// ---------------- combine the 2 kv-splits ----------------
__global__ __launch_bounds__(256) void attn_combine(const u16* __restrict__ o0,
                                                    const u16* __restrict__ o1,
                                                    const float2* __restrict__ ml,
                                                    u16* __restrict__ aout) {
  int g = blockIdx.x * 256 + threadIdx.x;
  int bth = g >> 3, j0 = (g & 7) * 8;
  int b = bth >> 15, t = (bth >> 4) & 2047, h = bth & 15;
  int mlidx = (((b << 4) | h) << 11) | t;
  float2 v0 = ml[mlidx];
  float2 v1 = ml[NB * NHEAD * TSEQ + mlidx];
  float M = fmaxf(v0.x, v1.x);
  float a0 = exp2fast(v0.x - M), a1 = exp2fast(v1.x - M);
  float rd = __fdividef(1.f, __builtin_fmaf(v0.y, a0, v1.y * a1));
  float s0 = a0 * rd, s1 = a1 * rd;
  size_t base = (size_t)bth * 64 + j0;
  s16x8 x0 = *(const s16x8*)(o0 + base);
  s16x8 x1 = *(const s16x8*)(o1 + base);
  s16x8 out;
#pragma unroll
  for (int j = 0; j < 8; ++j) {
    float f = __builtin_fmaf(bf2f((u16)x0[j]), s0, bf2f((u16)x1[j]) * s1);
    out[j] = (short)f2bf(f);
  }
  *(s16x8*)(aout + base) = out;
}

extern "C" void kernel_launch(void* const* d_in, const int* in_sizes, int n_in,
                              void* d_out, int out_size, void* d_ws, size_t ws_size,
                              hipStream_t stream) {
  const float* query = (const float*)d_in[0];
  const float* key_  = (const float*)d_in[1];
  const float* value = (const float*)d_in[2];
  const float* frac  = (const float*)d_in[3];
  const float* Wq    = (const float*)d_in[4];
  const float* bq    = (const float*)d_in[5];
  const float* Wk    = (const float*)d_in[6];
  const float* bk    = (const float*)d_in[7];
  const float* Wv    = (const float*)d_in[8];
  const float* bv    = (const float*)d_in[9];
  const float* abias = (const float*)d_in[10];
  const float* Wo    = (const float*)d_in[11];
  const float* bo    = (const float*)d_in[12];

  char* ws = (char*)d_ws;
  size_t off = 0;
  auto alloc = [&](size_t bytes) { char* p = ws + off; off += (bytes + 255) & ~255ULL; return p; };
  const size_t XB = (size_t)MROWS * D_MODEL * 2;
  const size_t WB = (size_t)D_MODEL * D_MODEL * 2;
  u16* qb  = (u16*)alloc(XB);
  u16* kb  = (u16*)alloc(XB);
  u16* vb  = (u16*)alloc(XB);
  u16* Wqb = (u16*)alloc(WB);
  u16* Wkb = (u16*)alloc(WB);
  u16* Wvb = (u16*)alloc(WB);
  u16* Wob = (u16*)alloc(WB);
  float* bsum = (float*)alloc(256);
  u16* Qp  = (u16*)alloc(XB);
  u16* Kp  = (u16*)alloc(XB);
  u16* Vtp = (u16*)alloc(XB);
  u16* AO  = (u16*)alloc(XB);

  // kv-split partial buffers reuse regions that are dead after gemm_qkv:
  u16* o0 = qb;                 // 8.39 MB
  u16* o1 = kb;                 // 8.39 MB
  float2* ml = (float2*)vb;     // 1 MB used

  cvt_all<<<dim3(16385), dim3(256), 0, stream>>>(query, key_, value, Wq, Wk, Wv, Wo, abias,
                                                 qb, kb, vb, Wqb, Wkb, Wvb, Wob, bsum);

  gemm_qkv<<<dim3(D_MODEL / 128, MROWS / 128, 3), dim3(256), 0, stream>>>(
      qb, kb, vb, Wqb, Wkb, Wvb, bq, bk, bv, Qp, Kp, Vtp);

  attn_kernel<<<dim3(TSEQ / 128, NB * NHEAD, NSPLIT), dim3(256), 0, stream>>>(
      Qp, Kp, Vtp, frac, bsum, o0, o1, ml);

  attn_combine<<<dim3(MROWS * D_MODEL / 8 / 256), dim3(256), 0, stream>>>(o0, o1, ml, AO);

  gemm_out<<<dim3(D_MODEL / 128, MROWS / 64), dim3(256), 0, stream>>>(AO, Wob, bo, (float*)d_out);
}